// Round 12
// baseline (304.749 us; speedup 1.0000x reference)
//
#include <hip/hip_runtime.h>

// Problem constants
#define NTOK 32768
#define DDIM 1024
#define HDIM 512
#define CDIM 512
#define NEXP 8

#define BM 128
#define BN 128
#define BKS 32        // K-step (double-buffered; 2 bufs == R8's single-buf LDS)
#define MAXTILE 520   // sum ceil(ne/128) <= 512 + 8

typedef __attribute__((ext_vector_type(8))) __bf16 bf16x8;
typedef __attribute__((ext_vector_type(4))) float f32x4;
typedef __attribute__((ext_vector_type(4))) unsigned short us4;
typedef __attribute__((ext_vector_type(8))) unsigned short us8;

static __device__ __forceinline__ unsigned short f2bf(float f) {
  union { float f; unsigned u; } v; v.f = f;
  unsigned u = v.u;
  u += 0x7FFFu + ((u >> 16) & 1u);   // RNE round to bf16
  return (unsigned short)(u >> 16);
}

static __device__ __forceinline__ float bf2f(unsigned short s) {
  union { unsigned u; float f; } v;
  v.u = ((unsigned)s) << 16;
  return v.f;
}

// HBM -> LDS direct DMA, 16B per lane. LDS dest = wave-uniform base + lane*16.
static __device__ __forceinline__ void gl_lds16(const void* g, void* l) {
  __builtin_amdgcn_global_load_lds(
      (const __attribute__((address_space(1))) unsigned int*)(unsigned long long)g,
      (__attribute__((address_space(3))) unsigned int*)(unsigned)(unsigned long long)l,
      16, 0, 0);
}

// Explicit LDS-DMA drain before barrier (R7 post-timing race fix; keep).
static __device__ __forceinline__ void fence_dma_then_barrier() {
  __builtin_amdgcn_sched_barrier(0);
  asm volatile("s_waitcnt vmcnt(0)" ::: "memory");
  __builtin_amdgcn_sched_barrier(0);
  __syncthreads();
}

// One pipeline fence per K-step: drain own DMAs (issued BEFORE this
// iteration's compute, so latency is covered), then block barrier.
static __device__ __forceinline__ void pipe_fence() {
  __builtin_amdgcn_sched_barrier(0);
  asm volatile("s_waitcnt vmcnt(0)" ::: "memory");
  __builtin_amdgcn_sched_barrier(0);
  __builtin_amdgcn_s_barrier();
  __builtin_amdgcn_sched_barrier(0);
}

// ---------------------------------------------------------------------------
// Transpose [E][R][Cc] fp32 -> [E][Cc][R] bf16
// ---------------------------------------------------------------------------
__global__ __launch_bounds__(256) void transpose_bf16_kernel(
    const float* __restrict__ in, unsigned short* __restrict__ out,
    int R, int Cc) {
  __shared__ float tile[32][33];
  int e = blockIdx.z;
  int c0 = blockIdx.x * 32, r0 = blockIdx.y * 32;
  const float* src = in + (size_t)e * R * Cc;
  unsigned short* dst = out + (size_t)e * R * Cc;
  int tx = threadIdx.x, ty = threadIdx.y;  // (32, 8)
#pragma unroll
  for (int i = 0; i < 32; i += 8)
    tile[ty + i][tx] = src[(size_t)(r0 + ty + i) * Cc + (c0 + tx)];
  __syncthreads();
#pragma unroll
  for (int i = 0; i < 32; i += 8)
    dst[(size_t)(c0 + ty + i) * R + (r0 + tx)] = f2bf(tile[tx][ty + i]);
}

// ---------------------------------------------------------------------------
// Gate v4 (measured best): scalar f32-Kahan logits + f64 combine, fused
// bf16-x emission. Wave-private x slab in LDS. No atomics.
// ---------------------------------------------------------------------------
#define GWPITCH 1064   // wg_lds expert pitch (words)
#define XSLOT 1056     // per-wave x slab words

__global__ __launch_bounds__(256) void gate_kernel(
    const float* __restrict__ x, const float* __restrict__ Wg,
    const float* __restrict__ bg, int* __restrict__ sel,
    float* __restrict__ wpair, unsigned short* __restrict__ xb) {
  __shared__ float wg_lds[NEXP * GWPITCH];   // ~34 KB, [e][d + 4*(d>>7)]
  __shared__ float xs[4][XSLOT];             // ~16.5 KB, per-wave slab

  int t = threadIdx.x;
  for (int i = t; i < DDIM * NEXP / 4; i += 256) {
    f32x4 v = *(const f32x4*)(Wg + (size_t)i * 4);
    int d = i >> 1;
    int e0 = (i & 1) * 4;
    int dsk = d + 4 * (d >> 7);
#pragma unroll
    for (int z = 0; z < 4; ++z)
      wg_lds[(e0 + z) * GWPITCH + dsk] = v[z];
  }
  __syncthreads();

  int wave = t >> 6, lane = t & 63;
  int g = lane >> 3, e = lane & 7;
  float* xslab = xs[wave];
  const float* wgrow = wg_lds + e * GWPITCH + g * 132;  // 128g + 4g skew
  const float* xsg = xslab + g * 132;
  double bge = (double)bg[e];

  int n0 = blockIdx.x * 32 + wave * 8;
  f32x4 ld[4], ldn[4];
  {
    const f32x4* xrow = (const f32x4*)(x + (size_t)n0 * DDIM);
#pragma unroll
    for (int j = 0; j < 4; ++j) ld[j] = xrow[j * 64 + lane];
  }

#pragma unroll 1
  for (int r = 0; r < 8; ++r) {
    int n = n0 + r;
    unsigned short* xbr = xb + (size_t)n * DDIM;
#pragma unroll
    for (int j = 0; j < 4; ++j) {
      int d0 = j * 256 + lane * 4;
      *(f32x4*)&xslab[d0 + 4 * (d0 >> 7)] = ld[j];
      us4 o;
#pragma unroll
      for (int z = 0; z < 4; ++z) o[z] = f2bf(ld[j][z]);
      *(us4*)&xbr[d0] = o;
    }
    if (r < 7) {
      const f32x4* xr2 = (const f32x4*)(x + (size_t)(n + 1) * DDIM);
#pragma unroll
      for (int j = 0; j < 4; ++j) ldn[j] = xr2[j * 64 + lane];
    }
    float s0 = 0.0f, c0 = 0.0f, s1 = 0.0f, c1 = 0.0f;
#pragma unroll
    for (int k = 0; k < 32; ++k) {
      f32x4 xv = *(const f32x4*)&xsg[4 * k];
      f32x4 wv = *(const f32x4*)&wgrow[4 * k];
#pragma unroll
      for (int z = 0; z < 4; z += 2) {
        float p0 = xv[z] * wv[z];
        float y0 = p0 - c0;
        float t0 = s0 + y0;
        c0 = (t0 - s0) - y0;
        s0 = t0;
        float p1 = xv[z + 1] * wv[z + 1];
        float y1 = p1 - c1;
        float t1 = s1 + y1;
        c1 = (t1 - s1) - y1;
        s1 = t1;
      }
    }
    double p = ((double)s0 + (double)c0) + ((double)s1 + (double)c1);
    p += __shfl_xor(p, 8, 64);
    p += __shfl_xor(p, 16, 64);
    p += __shfl_xor(p, 32, 64);
    double mylg = p + bge;
    double lg[NEXP];
#pragma unroll
    for (int ee = 0; ee < NEXP; ++ee) lg[ee] = __shfl(mylg, ee, 64);
    if (lane == 0) {
      int e0i = 0;
#pragma unroll
      for (int ee = 1; ee < NEXP; ++ee) if (lg[ee] > lg[e0i]) e0i = ee;  // earliest on tie
      int e1i = (e0i == 0) ? 1 : 0;
#pragma unroll
      for (int ee = 0; ee < NEXP; ++ee)
        if (ee != e0i && lg[ee] > lg[e1i]) e1i = ee;                     // earliest on tie
      float w1 = 1.0f / (1.0f + expf((float)(lg[e0i] - lg[e1i])));
      float w0 = 1.0f - w1;
      sel[n] = e0i | (e1i << 4);
      wpair[n * 2] = w0;
      wpair[n * 2 + 1] = w1;
    }
#pragma unroll
    for (int j = 0; j < 4; ++j) ld[j] = ldn[j];
  }
}

// ---------------------------------------------------------------------------
// Build per-expert pair lists via deterministic block-wide prefix scan.
// ---------------------------------------------------------------------------
__global__ __launch_bounds__(1024) void build_lists_kernel(
    const int* __restrict__ sel, int* __restrict__ counts,
    int* __restrict__ lists) {
  int e = blockIdx.x;
  int t = threadIdx.x;
  __shared__ int sc[1024];
  int base = t * (NTOK / 1024);
  int cnt = 0;
#pragma unroll
  for (int i = 0; i < NTOK / 1024; ++i) {
    int s = sel[base + i];
    cnt += ((s & 15) == e) || (((s >> 4) & 15) == e);
  }
  sc[t] = cnt;
  __syncthreads();
  for (int d = 1; d < 1024; d <<= 1) {
    int v = (t >= d) ? sc[t - d] : 0;
    __syncthreads();
    sc[t] += v;
    __syncthreads();
  }
  int off = sc[t] - cnt;
#pragma unroll
  for (int i = 0; i < NTOK / 1024; ++i) {
    int s = sel[base + i];
    if ((s & 15) == e)
      lists[e * NTOK + off++] = (base + i) * 2;
    else if (((s >> 4) & 15) == e)
      lists[e * NTOK + off++] = (base + i) * 2 + 1;
  }
  if (t == 1023) counts[e] = sc[1023];
}

// ---------------------------------------------------------------------------
// Tile table: tiles[0]=ntiles; tiles[1+2t]=expert, tiles[2+2t]=row0.
// ---------------------------------------------------------------------------
__global__ __launch_bounds__(256) void make_tiles_kernel(
    const int* __restrict__ counts, int* __restrict__ tiles) {
  __shared__ int off[NEXP + 1];
  int t = threadIdx.x;
  if (t == 0) {
    int s = 0;
    for (int e = 0; e < NEXP; ++e) { off[e] = s; s += (counts[e] + BM - 1) / BM; }
    off[NEXP] = s;
    tiles[0] = s;
  }
  __syncthreads();
  for (int e = 0; e < NEXP; ++e) {
    int base = off[e], cnt = off[e + 1] - off[e];
    for (int k = t; k < cnt; k += 256) {
      tiles[1 + 2 * (base + k)] = e;
      tiles[2 + 2 * (base + k)] = k * BM;
    }
  }
}

// ---------------------------------------------------------------------------
// XCD-chunked decode: grid = 65*4*8 = 2080 flat blocks.
// ---------------------------------------------------------------------------
static __device__ __forceinline__ bool decode_tile(
    const int* tiles, const int* counts, int& e, int& ne, int& row0, int& col0) {
  int i = blockIdx.x;
  int xcd = i & 7, slot = i >> 3;
  int col = slot & 3, tslot = slot >> 2;
  int rt = tslot * 8 + xcd;
  if (rt >= tiles[0]) return false;
  e = tiles[1 + 2 * rt];
  row0 = tiles[2 + 2 * rt];
  ne = counts[e];
  col0 = col * BN;
  return true;
}

// ---------------------------------------------------------------------------
// GEMM1: h[p,:] = relu( xb[tok(p),:] @ W1t[e]^T + b1[e] )  (bf16 out)
// BK=32 double-buffered gl_lds pipeline (T3 minimum-2-phase): issue next
// tile's DMA first, compute current, ONE vmcnt(0)+barrier per K-step.
// LDS footprint identical to R8 single-buffer (32 KB). 4-slot swizzle:
// source (t&3)^((t>>3)&3), read fg^((fr>>1)&3) -> 2-way (free).
// ---------------------------------------------------------------------------
__global__ __launch_bounds__(256) void gemm1_kernel(
    const unsigned short* __restrict__ xb, const unsigned short* __restrict__ W1t,
    const float* __restrict__ b1, const int* __restrict__ lists,
    const int* __restrict__ counts, const int* __restrict__ tiles,
    unsigned short* __restrict__ h) {
  int e, ne, row0, col0;
  if (!decode_tile(tiles, counts, e, ne, row0, col0)) return;

  __shared__ __attribute__((aligned(128))) unsigned short sA[2][BM * BKS];
  __shared__ __attribute__((aligned(128))) unsigned short sB[2][BN * BKS];
  __shared__ int sTok[BM];

  int t = threadIdx.x;
  if (t < BM) {
    int r = row0 + t;
    sTok[t] = (r < ne) ? lists[e * NTOK + r] : -1;
  }
  __syncthreads();

  // staging: pass j covers rows [j*64, j*64+64); thread t -> row j*64+(t>>2),
  // phys slot t&3; fetch logical slot (t&3)^((t>>3)&3) from global.
  int srow = t >> 2;
  int lslot = (t & 3) ^ ((t >> 3) & 3);
  const unsigned short* aSrc[2];
  const unsigned short* bSrc[2];
  int dOff[2];
  int wbase = (t >> 6) * 512;   // wave-uniform LDS dest (shorts)
#pragma unroll
  for (int j = 0; j < 2; ++j) {
    int p = sTok[j * 64 + srow];
    int tok = (p < 0) ? 0 : (p >> 1);
    aSrc[j] = xb + (size_t)tok * DDIM + lslot * 8;
    int c = col0 + j * 64 + srow;
    bSrc[j] = W1t + ((size_t)e * HDIM + c) * DDIM + lslot * 8;
    dOff[j] = j * 2048 + wbase;
  }

  int wave = t >> 6, lane = t & 63;
  int wr = wave >> 1, wc = wave & 1;
  int fr = lane & 15, fg = lane >> 4;
  int sl = (fg ^ ((fr >> 1) & 3)) * 8;   // swizzled read slot (shorts)

  f32x4 acc[4][4];
#pragma unroll
  for (int m = 0; m < 4; ++m)
#pragma unroll
    for (int nn = 0; nn < 4; ++nn) acc[m][nn] = (f32x4)0.0f;

#define G1_STAGE(buf, kt)                                         \
  {                                                               \
    _Pragma("unroll")                                             \
    for (int j = 0; j < 2; ++j) {                                 \
      gl_lds16(aSrc[j] + (kt) * BKS, &sA[buf][dOff[j]]);          \
      gl_lds16(bSrc[j] + (kt) * BKS, &sB[buf][dOff[j]]);          \
    }                                                             \
  }

#define G1_COMPUTE(buf)                                           \
  {                                                               \
    bf16x8 af[4], bfr[4];                                         \
    _Pragma("unroll")                                             \
    for (int m = 0; m < 4; ++m)                                   \
      af[m] = *(const bf16x8*)&sA[buf][(wr * 64 + m * 16 + fr) * BKS + sl]; \
    _Pragma("unroll")                                             \
    for (int nn = 0; nn < 4; ++nn)                                \
      bfr[nn] = *(const bf16x8*)&sB[buf][(wc * 64 + nn * 16 + fr) * BKS + sl]; \
    _Pragma("unroll")                                             \
    for (int m = 0; m < 4; ++m)                                   \
      _Pragma("unroll")                                           \
      for (int nn = 0; nn < 4; ++nn)                              \
        acc[m][nn] = __builtin_amdgcn_mfma_f32_16x16x32_bf16(     \
            af[m], bfr[nn], acc[m][nn], 0, 0, 0);                 \
  }

  const int NKT = DDIM / BKS;  // 32 (even)
  G1_STAGE(0, 0);
  fence_dma_then_barrier();
#pragma unroll 1
  for (int kt = 0; kt < NKT; kt += 2) {
    // even step: stage kt+1 -> buf1, compute buf0
    G1_STAGE(1, kt + 1);
    G1_COMPUTE(0);
    pipe_fence();
    // odd step: stage kt+2 -> buf0 (if any), compute buf1
    if (kt + 2 < NKT) G1_STAGE(0, kt + 2);
    G1_COMPUTE(1);
    pipe_fence();
  }
#undef G1_STAGE
#undef G1_COMPUTE

  int cBase = col0 + wc * 64 + fr;
  float b1c[4];
#pragma unroll
  for (int nn = 0; nn < 4; ++nn) b1c[nn] = b1[e * HDIM + cBase + nn * 16];
#pragma unroll
  for (int m = 0; m < 4; ++m) {
#pragma unroll
    for (int q = 0; q < 4; ++q) {
      int rloc = wr * 64 + m * 16 + fg * 4 + q;
      if (row0 + rloc < ne) {
        int p = sTok[rloc];
        unsigned short* hr = h + (size_t)p * HDIM;
#pragma unroll
        for (int nn = 0; nn < 4; ++nn) {
          float v = acc[m][nn][q] + b1c[nn];
          v = fmaxf(v, 0.0f);
          hr[cBase + nn * 16] = f2bf(v);
        }
      }
    }
  }
}

// ---------------------------------------------------------------------------
// GEMM2: obuf[p,:] = h[p,:] @ W2t[e]^T + b2[e]  (bf16, NO atomics)
// Same BK=32 double-buffered pipeline.
// ---------------------------------------------------------------------------
__global__ __launch_bounds__(256) void gemm2_kernel(
    const unsigned short* __restrict__ h, const unsigned short* __restrict__ W2t,
    const float* __restrict__ b2, const int* __restrict__ lists,
    const int* __restrict__ counts, const int* __restrict__ tiles,
    unsigned short* __restrict__ obuf) {
  int e, ne, row0, col0;
  if (!decode_tile(tiles, counts, e, ne, row0, col0)) return;

  __shared__ __attribute__((aligned(128))) unsigned short sA[2][BM * BKS];
  __shared__ __attribute__((aligned(128))) unsigned short sB[2][BN * BKS];
  __shared__ int sTok[BM];

  int t = threadIdx.x;
  if (t < BM) {
    int r = row0 + t;
    sTok[t] = (r < ne) ? lists[e * NTOK + r] : -1;
  }
  __syncthreads();

  int srow = t >> 2;
  int lslot = (t & 3) ^ ((t >> 3) & 3);
  const unsigned short* aSrc[2];
  const unsigned short* bSrc[2];
  int dOff[2];
  int wbase = (t >> 6) * 512;
#pragma unroll
  for (int j = 0; j < 2; ++j) {
    int p = sTok[j * 64 + srow];
    int pp = (p < 0) ? 0 : p;
    aSrc[j] = h + (size_t)pp * HDIM + lslot * 8;
    int c = col0 + j * 64 + srow;
    bSrc[j] = W2t + ((size_t)e * CDIM + c) * HDIM + lslot * 8;
    dOff[j] = j * 2048 + wbase;
  }

  int wave = t >> 6, lane = t & 63;
  int wr = wave >> 1, wc = wave & 1;
  int fr = lane & 15, fg = lane >> 4;
  int sl = (fg ^ ((fr >> 1) & 3)) * 8;

  f32x4 acc[4][4];
#pragma unroll
  for (int m = 0; m < 4; ++m)
#pragma unroll
    for (int nn = 0; nn < 4; ++nn) acc[m][nn] = (f32x4)0.0f;

#define G2_STAGE(buf, kt)                                         \
  {                                                               \
    _Pragma("unroll")                                             \
    for (int j = 0; j < 2; ++j) {                                 \
      gl_lds16(aSrc[j] + (kt) * BKS, &sA[buf][dOff[j]]);          \
      gl_lds16(bSrc[j] + (kt) * BKS, &sB[buf][dOff[j]]);          \
    }                                                             \
  }

#define G2_COMPUTE(buf)                                           \
  {                                                               \
    bf16x8 af[4], bfr[4];                                         \
    _Pragma("unroll")                                             \
    for (int m = 0; m < 4; ++m)                                   \
      af[m] = *(const bf16x8*)&sA[buf][(wr * 64 + m * 16 + fr) * BKS + sl]; \
    _Pragma("unroll")                                             \
    for (int nn = 0; nn < 4; ++nn)                                \
      bfr[nn] = *(const bf16x8*)&sB[buf][(wc * 64 + nn * 16 + fr) * BKS + sl]; \
    _Pragma("unroll")                                             \
    for (int m = 0; m < 4; ++m)                                   \
      _Pragma("unroll")                                           \
      for (int nn = 0; nn < 4; ++nn)                              \
        acc[m][nn] = __builtin_amdgcn_mfma_f32_16x16x32_bf16(     \
            af[m], bfr[nn], acc[m][nn], 0, 0, 0);                 \
  }

  const int NKT = HDIM / BKS;  // 16 (even)
  G2_STAGE(0, 0);
  fence_dma_then_barrier();
#pragma unroll 1
  for (int kt = 0; kt < NKT; kt += 2) {
    G2_STAGE(1, kt + 1);
    G2_COMPUTE(0);
    pipe_fence();
    if (kt + 2 < NKT) G2_STAGE(0, kt + 2);
    G2_COMPUTE(1);
    pipe_fence();
  }
#undef G2_STAGE
#undef G2_COMPUTE

  int cBase = col0 + wc * 64 + fr;
  float b2c[4];
#pragma unroll
  for (int nn = 0; nn < 4; ++nn) b2c[nn] = b2[e * CDIM + cBase + nn * 16];
#pragma unroll
  for (int m = 0; m < 4; ++m) {
#pragma unroll
    for (int q = 0; q < 4; ++q) {
      int rloc = wr * 64 + m * 16 + fg * 4 + q;
      if (row0 + rloc < ne) {
        int p = sTok[rloc];
        unsigned short* orow = obuf + (size_t)p * CDIM;
#pragma unroll
        for (int nn = 0; nn < 4; ++nn)
          orow[cBase + nn * 16] = f2bf(acc[m][nn][q] + b2c[nn]);
      }
    }
  }
}

// ---------------------------------------------------------------------------
// Combine (in-place on d_out): out[n] = w0*obuf[2n] + w1*obuf[2n+1].
// ---------------------------------------------------------------------------
__global__ __launch_bounds__(256) void combine_kernel(
    const float* __restrict__ wpair, float* __restrict__ out) {
  const unsigned short* obuf = (const unsigned short*)out;
  int t = threadIdx.x;
  int n = blockIdx.x * 4 + (t >> 6);
  int c = (t & 63) * 8;
  us8 a = *(const us8*)&obuf[(size_t)(2 * n) * CDIM + c];
  us8 b = *(const us8*)&obuf[(size_t)(2 * n + 1) * CDIM + c];
  float w0 = wpair[2 * n], w1 = wpair[2 * n + 1];
  f32x4 r0, r1;
#pragma unroll
  for (int z = 0; z < 4; ++z) {
    r0[z] = w0 * bf2f(a[z]) + w1 * bf2f(b[z]);
    r1[z] = w0 * bf2f(a[z + 4]) + w1 * bf2f(b[z + 4]);
  }
  __syncthreads();
  *(f32x4*)&out[(size_t)n * CDIM + c] = r0;
  *(f32x4*)&out[(size_t)n * CDIM + c + 4] = r1;
}

// ---------------------------------------------------------------------------
extern "C" void kernel_launch(void* const* d_in, const int* in_sizes, int n_in,
                              void* d_out, int out_size, void* d_ws, size_t ws_size,
                              hipStream_t stream) {
  const float* x  = (const float*)d_in[0];
  const float* W1 = (const float*)d_in[1];
  const float* b1 = (const float*)d_in[2];
  const float* W2 = (const float*)d_in[3];
  const float* b2 = (const float*)d_in[4];
  const float* Wg = (const float*)d_in[5];
  const float* bg = (const float*)d_in[6];
  float* out = (float*)d_out;
  char* ws = (char*)d_ws;

  // workspace layout (~77.4 MiB)
  int* counts = (int*)ws;                                    // 256 B
  float* wpair = (float*)(ws + 256);                         // 256 KiB
  int* sel = (int*)(ws + 256 + 262144);                      // 128 KiB
  int* lists = (int*)(ws + 256 + 262144 + 131072);           // 1 MiB
  int* tiles = (int*)(ws + 256 + 262144 + 131072 + 1048576); // 8 KiB
  unsigned short* W1t = (unsigned short*)(ws + 256 + 262144 + 131072 + 1048576 + 8192);
  unsigned short* W2t = W1t + (size_t)NEXP * HDIM * DDIM;    // +8 MiB
  unsigned short* hbuf = W2t + (size_t)NEXP * CDIM * HDIM;   // +4 MiB, hbuf 64 MiB

  // d_out (64 MiB) triple-duty: xb (bf16 x) -> obuf (bf16 pair-rows) -> out.
  unsigned short* xb = (unsigned short*)d_out;
  unsigned short* obuf = (unsigned short*)d_out;

  hipLaunchKernelGGL(transpose_bf16_kernel, dim3(HDIM / 32, DDIM / 32, NEXP),
                     dim3(32, 8), 0, stream, W1, W1t, DDIM, HDIM);
  hipLaunchKernelGGL(transpose_bf16_kernel, dim3(CDIM / 32, HDIM / 32, NEXP),
                     dim3(32, 8), 0, stream, W2, W2t, HDIM, CDIM);
  hipLaunchKernelGGL(gate_kernel, dim3(NTOK / 32), dim3(256), 0, stream,
                     x, Wg, bg, sel, wpair, xb);
  hipLaunchKernelGGL(build_lists_kernel, dim3(NEXP), dim3(1024), 0, stream,
                     sel, counts, lists);
  hipLaunchKernelGGL(make_tiles_kernel, dim3(1), dim3(256), 0, stream,
                     counts, tiles);
  hipLaunchKernelGGL(gemm1_kernel, dim3((MAXTILE / 8) * 4 * 8), dim3(256),
                     0, stream, xb, W1t, b1, lists, counts, tiles, hbuf);
  hipLaunchKernelGGL(gemm2_kernel, dim3((MAXTILE / 8) * 4 * 8), dim3(256),
                     0, stream, hbuf, W2t, b2, lists, counts, tiles, obuf);
  hipLaunchKernelGGL(combine_kernel, dim3(NTOK / 4), dim3(256), 0, stream,
                     wpair, out);
}

// Round 13
// 246.595 us; speedup vs baseline: 1.2358x; 1.2358x over previous
//
#include <hip/hip_runtime.h>

// Problem constants
#define NTOK 32768
#define DDIM 1024
#define HDIM 512
#define CDIM 512
#define NEXP 8

#define BM 128
#define BN 128
#define BK 64
#define MAXTILE 520   // sum ceil(ne/128) <= 512 + 8

typedef __attribute__((ext_vector_type(8))) __bf16 bf16x8;
typedef __attribute__((ext_vector_type(4))) float f32x4;
typedef __attribute__((ext_vector_type(4))) unsigned short us4;
typedef __attribute__((ext_vector_type(8))) unsigned short us8;

static __device__ __forceinline__ unsigned short f2bf(float f) {
  union { float f; unsigned u; } v; v.f = f;
  unsigned u = v.u;
  u += 0x7FFFu + ((u >> 16) & 1u);   // RNE round to bf16
  return (unsigned short)(u >> 16);
}

static __device__ __forceinline__ float bf2f(unsigned short s) {
  union { unsigned u; float f; } v;
  v.u = ((unsigned)s) << 16;
  return v.f;
}

// HBM -> LDS direct DMA, 16B per lane. LDS dest = wave-uniform base + lane*16.
static __device__ __forceinline__ void gl_lds16(const void* g, void* l) {
  __builtin_amdgcn_global_load_lds(
      (const __attribute__((address_space(1))) unsigned int*)(unsigned long long)g,
      (__attribute__((address_space(3))) unsigned int*)(unsigned)(unsigned long long)l,
      16, 0, 0);
}

// Explicit LDS-DMA drain before barrier (R7 post-timing race fix; keep).
static __device__ __forceinline__ void fence_dma_then_barrier() {
  __builtin_amdgcn_sched_barrier(0);
  asm volatile("s_waitcnt vmcnt(0)" ::: "memory");
  __builtin_amdgcn_sched_barrier(0);
  __syncthreads();
}

static __device__ __forceinline__ void fence_lds_then_barrier() {
  __builtin_amdgcn_sched_barrier(0);
  asm volatile("s_waitcnt lgkmcnt(0)" ::: "memory");
  __builtin_amdgcn_sched_barrier(0);
  __syncthreads();
}

// ---------------------------------------------------------------------------
// Transpose [E][R][Cc] fp32 -> [E][Cc][R] bf16
// ---------------------------------------------------------------------------
__global__ __launch_bounds__(256) void transpose_bf16_kernel(
    const float* __restrict__ in, unsigned short* __restrict__ out,
    int R, int Cc) {
  __shared__ float tile[32][33];
  int e = blockIdx.z;
  int c0 = blockIdx.x * 32, r0 = blockIdx.y * 32;
  const float* src = in + (size_t)e * R * Cc;
  unsigned short* dst = out + (size_t)e * R * Cc;
  int tx = threadIdx.x, ty = threadIdx.y;  // (32, 8)
#pragma unroll
  for (int i = 0; i < 32; i += 8)
    tile[ty + i][tx] = src[(size_t)(r0 + ty + i) * Cc + (c0 + tx)];
  __syncthreads();
#pragma unroll
  for (int i = 0; i < 32; i += 8)
    dst[(size_t)(c0 + ty + i) * R + (r0 + tx)] = f2bf(tile[tx][ty + i]);
}

// ---------------------------------------------------------------------------
// Gate v4 (measured best): scalar f32-Kahan logits + f64 combine, fused
// bf16-x emission. 1024 blocks x 4 waves; each wave owns 8 rows. Lane (g,e):
// g=lane>>3 owns d in [128g,128g+128) for expert e=lane&7. Wave-private x
// slab in LDS (skewed +4 words per 128-block). No atomics; no barriers in
// the row loop.
// ---------------------------------------------------------------------------
#define GWPITCH 1064   // wg_lds expert pitch (words)
#define XSLOT 1056     // per-wave x slab words

__global__ __launch_bounds__(256) void gate_kernel(
    const float* __restrict__ x, const float* __restrict__ Wg,
    const float* __restrict__ bg, int* __restrict__ sel,
    float* __restrict__ wpair, unsigned short* __restrict__ xb) {
  __shared__ float wg_lds[NEXP * GWPITCH];   // ~34 KB, [e][d + 4*(d>>7)]
  __shared__ float xs[4][XSLOT];             // ~16.5 KB, per-wave slab

  int t = threadIdx.x;
  for (int i = t; i < DDIM * NEXP / 4; i += 256) {
    f32x4 v = *(const f32x4*)(Wg + (size_t)i * 4);
    int d = i >> 1;
    int e0 = (i & 1) * 4;
    int dsk = d + 4 * (d >> 7);
#pragma unroll
    for (int z = 0; z < 4; ++z)
      wg_lds[(e0 + z) * GWPITCH + dsk] = v[z];
  }
  __syncthreads();

  int wave = t >> 6, lane = t & 63;
  int g = lane >> 3, e = lane & 7;
  float* xslab = xs[wave];
  const float* wgrow = wg_lds + e * GWPITCH + g * 132;  // 128g + 4g skew
  const float* xsg = xslab + g * 132;
  double bge = (double)bg[e];

  int n0 = blockIdx.x * 32 + wave * 8;
  f32x4 ld[4], ldn[4];
  {
    const f32x4* xrow = (const f32x4*)(x + (size_t)n0 * DDIM);
#pragma unroll
    for (int j = 0; j < 4; ++j) ld[j] = xrow[j * 64 + lane];
  }

#pragma unroll 1
  for (int r = 0; r < 8; ++r) {
    int n = n0 + r;
    unsigned short* xbr = xb + (size_t)n * DDIM;
#pragma unroll
    for (int j = 0; j < 4; ++j) {
      int d0 = j * 256 + lane * 4;
      *(f32x4*)&xslab[d0 + 4 * (d0 >> 7)] = ld[j];
      us4 o;
#pragma unroll
      for (int z = 0; z < 4; ++z) o[z] = f2bf(ld[j][z]);
      *(us4*)&xbr[d0] = o;
    }
    if (r < 7) {
      const f32x4* xr2 = (const f32x4*)(x + (size_t)(n + 1) * DDIM);
#pragma unroll
      for (int j = 0; j < 4; ++j) ldn[j] = xr2[j * 64 + lane];
    }
    float s0 = 0.0f, c0 = 0.0f, s1 = 0.0f, c1 = 0.0f;
#pragma unroll
    for (int k = 0; k < 32; ++k) {
      f32x4 xv = *(const f32x4*)&xsg[4 * k];
      f32x4 wv = *(const f32x4*)&wgrow[4 * k];
#pragma unroll
      for (int z = 0; z < 4; z += 2) {
        float p0 = xv[z] * wv[z];
        float y0 = p0 - c0;
        float t0 = s0 + y0;
        c0 = (t0 - s0) - y0;
        s0 = t0;
        float p1 = xv[z + 1] * wv[z + 1];
        float y1 = p1 - c1;
        float t1 = s1 + y1;
        c1 = (t1 - s1) - y1;
        s1 = t1;
      }
    }
    double p = ((double)s0 + (double)c0) + ((double)s1 + (double)c1);
    p += __shfl_xor(p, 8, 64);
    p += __shfl_xor(p, 16, 64);
    p += __shfl_xor(p, 32, 64);
    double mylg = p + bge;
    double lg[NEXP];
#pragma unroll
    for (int ee = 0; ee < NEXP; ++ee) lg[ee] = __shfl(mylg, ee, 64);
    if (lane == 0) {
      int e0i = 0;
#pragma unroll
      for (int ee = 1; ee < NEXP; ++ee) if (lg[ee] > lg[e0i]) e0i = ee;  // earliest on tie
      int e1i = (e0i == 0) ? 1 : 0;
#pragma unroll
      for (int ee = 0; ee < NEXP; ++ee)
        if (ee != e0i && lg[ee] > lg[e1i]) e1i = ee;                     // earliest on tie
      float w1 = 1.0f / (1.0f + expf((float)(lg[e0i] - lg[e1i])));
      float w0 = 1.0f - w1;
      sel[n] = e0i | (e1i << 4);
      wpair[n * 2] = w0;
      wpair[n * 2 + 1] = w1;
    }
#pragma unroll
    for (int j = 0; j < 4; ++j) ld[j] = ldn[j];
  }
}

// ---------------------------------------------------------------------------
// Build per-expert pair lists via deterministic block-wide prefix scan.
// ---------------------------------------------------------------------------
__global__ __launch_bounds__(1024) void build_lists_kernel(
    const int* __restrict__ sel, int* __restrict__ counts,
    int* __restrict__ lists) {
  int e = blockIdx.x;
  int t = threadIdx.x;
  __shared__ int sc[1024];
  int base = t * (NTOK / 1024);
  int cnt = 0;
#pragma unroll
  for (int i = 0; i < NTOK / 1024; ++i) {
    int s = sel[base + i];
    cnt += ((s & 15) == e) || (((s >> 4) & 15) == e);
  }
  sc[t] = cnt;
  __syncthreads();
  for (int d = 1; d < 1024; d <<= 1) {
    int v = (t >= d) ? sc[t - d] : 0;
    __syncthreads();
    sc[t] += v;
    __syncthreads();
  }
  int off = sc[t] - cnt;
#pragma unroll
  for (int i = 0; i < NTOK / 1024; ++i) {
    int s = sel[base + i];
    if ((s & 15) == e)
      lists[e * NTOK + off++] = (base + i) * 2;
    else if (((s >> 4) & 15) == e)
      lists[e * NTOK + off++] = (base + i) * 2 + 1;
  }
  if (t == 1023) counts[e] = sc[1023];
}

// ---------------------------------------------------------------------------
// Tile table: tiles[0]=ntiles; tiles[1+2t]=expert, tiles[2+2t]=row0.
// ---------------------------------------------------------------------------
__global__ __launch_bounds__(256) void make_tiles_kernel(
    const int* __restrict__ counts, int* __restrict__ tiles) {
  __shared__ int off[NEXP + 1];
  int t = threadIdx.x;
  if (t == 0) {
    int s = 0;
    for (int e = 0; e < NEXP; ++e) { off[e] = s; s += (counts[e] + BM - 1) / BM; }
    off[NEXP] = s;
    tiles[0] = s;
  }
  __syncthreads();
  for (int e = 0; e < NEXP; ++e) {
    int base = off[e], cnt = off[e + 1] - off[e];
    for (int k = t; k < cnt; k += 256) {
      tiles[1 + 2 * (base + k)] = e;
      tiles[2 + 2 * (base + k)] = k * BM;
    }
  }
}

// ---------------------------------------------------------------------------
// XCD-chunked decode: grid = 65*4*8 = 2080 flat blocks.
// ---------------------------------------------------------------------------
static __device__ __forceinline__ bool decode_tile(
    const int* tiles, const int* counts, int& e, int& ne, int& row0, int& col0) {
  int i = blockIdx.x;
  int xcd = i & 7, slot = i >> 3;
  int col = slot & 3, tslot = slot >> 2;
  int rt = tslot * 8 + xcd;
  if (rt >= tiles[0]) return false;
  e = tiles[1 + 2 * rt];
  row0 = tiles[2 + 2 * rt];
  ne = counts[e];
  col0 = col * BN;
  return true;
}

// ---------------------------------------------------------------------------
// GEMM1: h[p,:] = relu( xb[tok(p),:] @ W1t[e]^T + b1[e] )  (bf16 out)
// global_load_lds staging, single linear [128][64] LDS tiles, XOR slot^(row&7)
// swizzle on per-lane SOURCE address + on the READ. Explicit DMA fences.
// ---------------------------------------------------------------------------
__global__ __launch_bounds__(256) void gemm1_kernel(
    const unsigned short* __restrict__ xb, const unsigned short* __restrict__ W1t,
    const float* __restrict__ b1, const int* __restrict__ lists,
    const int* __restrict__ counts, const int* __restrict__ tiles,
    unsigned short* __restrict__ h) {
  int e, ne, row0, col0;
  if (!decode_tile(tiles, counts, e, ne, row0, col0)) return;

  __shared__ __attribute__((aligned(128))) unsigned short sA[BM * BK];
  __shared__ __attribute__((aligned(128))) unsigned short sB[BN * BK];
  __shared__ int sTok[BM];

  int t = threadIdx.x;
  if (t < BM) {
    int r = row0 + t;
    sTok[t] = (r < ne) ? lists[e * NTOK + r] : -1;
  }
  __syncthreads();

  int srow = t >> 3;
  int sslot = (t & 7) ^ (srow & 7);
  const unsigned short* aSrc[4];
  const unsigned short* bSrc[4];
  unsigned short* aDst[4];
  unsigned short* bDst[4];
  int wbase = (t >> 6) * 512;   // wave-uniform LDS dest (shorts)
#pragma unroll
  for (int j = 0; j < 4; ++j) {
    int p = sTok[j * 32 + srow];
    int tok = (p < 0) ? 0 : (p >> 1);
    aSrc[j] = xb + (size_t)tok * DDIM + sslot * 8;
    int c = col0 + j * 32 + srow;
    bSrc[j] = W1t + ((size_t)e * HDIM + c) * DDIM + sslot * 8;
    aDst[j] = &sA[j * 2048 + wbase];
    bDst[j] = &sB[j * 2048 + wbase];
  }

  int wave = t >> 6, lane = t & 63;
  int wr = wave >> 1, wc = wave & 1;
  int fr = lane & 15, fg = lane >> 4;

  f32x4 acc[4][4];
#pragma unroll
  for (int m = 0; m < 4; ++m)
#pragma unroll
    for (int nn = 0; nn < 4; ++nn) acc[m][nn] = (f32x4)0.0f;

  const int NKT = DDIM / BK;  // 16
  for (int kt = 0; kt < NKT; ++kt) {
#pragma unroll
    for (int j = 0; j < 4; ++j) {
      gl_lds16(aSrc[j] + kt * BK, aDst[j]);
      gl_lds16(bSrc[j] + kt * BK, bDst[j]);
    }
    fence_dma_then_barrier();
#pragma unroll
    for (int ks = 0; ks < 2; ++ks) {
      int sl = (fg + ks * 4) ^ (fr & 7);   // swizzled read slot
      bf16x8 af[4], bfr[4];
#pragma unroll
      for (int m = 0; m < 4; ++m)
        af[m] = *(const bf16x8*)&sA[(wr * 64 + m * 16 + fr) * 64 + sl * 8];
#pragma unroll
      for (int nn = 0; nn < 4; ++nn)
        bfr[nn] = *(const bf16x8*)&sB[(wc * 64 + nn * 16 + fr) * 64 + sl * 8];
#pragma unroll
      for (int m = 0; m < 4; ++m)
#pragma unroll
        for (int nn = 0; nn < 4; ++nn)
          acc[m][nn] = __builtin_amdgcn_mfma_f32_16x16x32_bf16(
              af[m], bfr[nn], acc[m][nn], 0, 0, 0);
    }
    fence_lds_then_barrier();
  }

  int cBase = col0 + wc * 64 + fr;
  float b1c[4];
#pragma unroll
  for (int nn = 0; nn < 4; ++nn) b1c[nn] = b1[e * HDIM + cBase + nn * 16];
#pragma unroll
  for (int m = 0; m < 4; ++m) {
#pragma unroll
    for (int q = 0; q < 4; ++q) {
      int rloc = wr * 64 + m * 16 + fg * 4 + q;
      if (row0 + rloc < ne) {
        int p = sTok[rloc];
        unsigned short* hr = h + (size_t)p * HDIM;
#pragma unroll
        for (int nn = 0; nn < 4; ++nn) {
          float v = acc[m][nn][q] + b1c[nn];
          v = fmaxf(v, 0.0f);
          hr[cBase + nn * 16] = f2bf(v);
        }
      }
    }
  }
}

// ---------------------------------------------------------------------------
// GEMM2: obuf[p,:] = h[p,:] @ W2t[e]^T + b2[e]  (bf16, NO atomics)
// ---------------------------------------------------------------------------
__global__ __launch_bounds__(256) void gemm2_kernel(
    const unsigned short* __restrict__ h, const unsigned short* __restrict__ W2t,
    const float* __restrict__ b2, const int* __restrict__ lists,
    const int* __restrict__ counts, const int* __restrict__ tiles,
    unsigned short* __restrict__ obuf) {
  int e, ne, row0, col0;
  if (!decode_tile(tiles, counts, e, ne, row0, col0)) return;

  __shared__ __attribute__((aligned(128))) unsigned short sA[BM * BK];
  __shared__ __attribute__((aligned(128))) unsigned short sB[BN * BK];
  __shared__ int sTok[BM];

  int t = threadIdx.x;
  if (t < BM) {
    int r = row0 + t;
    sTok[t] = (r < ne) ? lists[e * NTOK + r] : -1;
  }
  __syncthreads();

  int srow = t >> 3;
  int sslot = (t & 7) ^ (srow & 7);
  const unsigned short* aSrc[4];
  const unsigned short* bSrc[4];
  unsigned short* aDst[4];
  unsigned short* bDst[4];
  int wbase = (t >> 6) * 512;
#pragma unroll
  for (int j = 0; j < 4; ++j) {
    int p = sTok[j * 32 + srow];
    int pp = (p < 0) ? 0 : p;
    aSrc[j] = h + (size_t)pp * HDIM + sslot * 8;
    int c = col0 + j * 32 + srow;
    bSrc[j] = W2t + ((size_t)e * CDIM + c) * HDIM + sslot * 8;
    aDst[j] = &sA[j * 2048 + wbase];
    bDst[j] = &sB[j * 2048 + wbase];
  }

  int wave = t >> 6, lane = t & 63;
  int wr = wave >> 1, wc = wave & 1;
  int fr = lane & 15, fg = lane >> 4;

  f32x4 acc[4][4];
#pragma unroll
  for (int m = 0; m < 4; ++m)
#pragma unroll
    for (int nn = 0; nn < 4; ++nn) acc[m][nn] = (f32x4)0.0f;

  const int NKT = HDIM / BK;  // 8
  for (int kt = 0; kt < NKT; ++kt) {
#pragma unroll
    for (int j = 0; j < 4; ++j) {
      gl_lds16(aSrc[j] + kt * BK, aDst[j]);
      gl_lds16(bSrc[j] + kt * BK, bDst[j]);
    }
    fence_dma_then_barrier();
#pragma unroll
    for (int ks = 0; ks < 2; ++ks) {
      int sl = (fg + ks * 4) ^ (fr & 7);
      bf16x8 af[4], bfr[4];
#pragma unroll
      for (int m = 0; m < 4; ++m)
        af[m] = *(const bf16x8*)&sA[(wr * 64 + m * 16 + fr) * 64 + sl * 8];
#pragma unroll
      for (int nn = 0; nn < 4; ++nn)
        bfr[nn] = *(const bf16x8*)&sB[(wc * 64 + nn * 16 + fr) * 64 + sl * 8];
#pragma unroll
      for (int m = 0; m < 4; ++m)
#pragma unroll
        for (int nn = 0; nn < 4; ++nn)
          acc[m][nn] = __builtin_amdgcn_mfma_f32_16x16x32_bf16(
              af[m], bfr[nn], acc[m][nn], 0, 0, 0);
    }
    fence_lds_then_barrier();
  }

  int cBase = col0 + wc * 64 + fr;
  float b2c[4];
#pragma unroll
  for (int nn = 0; nn < 4; ++nn) b2c[nn] = b2[e * CDIM + cBase + nn * 16];
#pragma unroll
  for (int m = 0; m < 4; ++m) {
#pragma unroll
    for (int q = 0; q < 4; ++q) {
      int rloc = wr * 64 + m * 16 + fg * 4 + q;
      if (row0 + rloc < ne) {
        int p = sTok[rloc];
        unsigned short* orow = obuf + (size_t)p * CDIM;
#pragma unroll
        for (int nn = 0; nn < 4; ++nn)
          orow[cBase + nn * 16] = f2bf(acc[m][nn][q] + b2c[nn]);
      }
    }
  }
}

// ---------------------------------------------------------------------------
// Combine (in-place on d_out): out[n] = w0*obuf[2n] + w1*obuf[2n+1].
// Block b owns f32 rows [4b,4b+4) == byte range of pair rows [8b,8b+8):
// read-all -> barrier -> write-all; no cross-block overlap.
// ---------------------------------------------------------------------------
__global__ __launch_bounds__(256) void combine_kernel(
    const float* __restrict__ wpair, float* __restrict__ out) {
  const unsigned short* obuf = (const unsigned short*)out;
  int t = threadIdx.x;
  int n = blockIdx.x * 4 + (t >> 6);
  int c = (t & 63) * 8;
  us8 a = *(const us8*)&obuf[(size_t)(2 * n) * CDIM + c];
  us8 b = *(const us8*)&obuf[(size_t)(2 * n + 1) * CDIM + c];
  float w0 = wpair[2 * n], w1 = wpair[2 * n + 1];
  f32x4 r0, r1;
#pragma unroll
  for (int z = 0; z < 4; ++z) {
    r0[z] = w0 * bf2f(a[z]) + w1 * bf2f(b[z]);
    r1[z] = w0 * bf2f(a[z + 4]) + w1 * bf2f(b[z + 4]);
  }
  __syncthreads();
  *(f32x4*)&out[(size_t)n * CDIM + c] = r0;
  *(f32x4*)&out[(size_t)n * CDIM + c + 4] = r1;
}

// ---------------------------------------------------------------------------
extern "C" void kernel_launch(void* const* d_in, const int* in_sizes, int n_in,
                              void* d_out, int out_size, void* d_ws, size_t ws_size,
                              hipStream_t stream) {
  const float* x  = (const float*)d_in[0];
  const float* W1 = (const float*)d_in[1];
  const float* b1 = (const float*)d_in[2];
  const float* W2 = (const float*)d_in[3];
  const float* b2 = (const float*)d_in[4];
  const float* Wg = (const float*)d_in[5];
  const float* bg = (const float*)d_in[6];
  float* out = (float*)d_out;
  char* ws = (char*)d_ws;

  // workspace layout (~77.4 MiB)
  int* counts = (int*)ws;                                    // 256 B
  float* wpair = (float*)(ws + 256);                         // 256 KiB
  int* sel = (int*)(ws + 256 + 262144);                      // 128 KiB
  int* lists = (int*)(ws + 256 + 262144 + 131072);           // 1 MiB
  int* tiles = (int*)(ws + 256 + 262144 + 131072 + 1048576); // 8 KiB
  unsigned short* W1t = (unsigned short*)(ws + 256 + 262144 + 131072 + 1048576 + 8192);
  unsigned short* W2t = W1t + (size_t)NEXP * HDIM * DDIM;    // +8 MiB
  unsigned short* hbuf = W2t + (size_t)NEXP * CDIM * HDIM;   // +4 MiB, hbuf 64 MiB

  // d_out (64 MiB) triple-duty: xb (bf16 x) -> obuf (bf16 pair-rows) -> out.
  unsigned short* xb = (unsigned short*)d_out;
  unsigned short* obuf = (unsigned short*)d_out;

  hipLaunchKernelGGL(transpose_bf16_kernel, dim3(HDIM / 32, DDIM / 32, NEXP),
                     dim3(32, 8), 0, stream, W1, W1t, DDIM, HDIM);
  hipLaunchKernelGGL(transpose_bf16_kernel, dim3(CDIM / 32, HDIM / 32, NEXP),
                     dim3(32, 8), 0, stream, W2, W2t, HDIM, CDIM);
  hipLaunchKernelGGL(gate_kernel, dim3(NTOK / 32), dim3(256), 0, stream,
                     x, Wg, bg, sel, wpair, xb);
  hipLaunchKernelGGL(build_lists_kernel, dim3(NEXP), dim3(1024), 0, stream,
                     sel, counts, lists);
  hipLaunchKernelGGL(make_tiles_kernel, dim3(1), dim3(256), 0, stream,
                     counts, tiles);
  hipLaunchKernelGGL(gemm1_kernel, dim3((MAXTILE / 8) * 4 * 8), dim3(256),
                     0, stream, xb, W1t, b1, lists, counts, tiles, hbuf);
  hipLaunchKernelGGL(gemm2_kernel, dim3((MAXTILE / 8) * 4 * 8), dim3(256),
                     0, stream, hbuf, W2t, b2, lists, counts, tiles, obuf);
  hipLaunchKernelGGL(combine_kernel, dim3(NTOK / 4), dim3(256), 0, stream,
                     wpair, out);
}